// Round 7
// baseline (95.295 us; speedup 1.0000x reference)
//
#include <hip/hip_runtime.h>
#include <math.h>

#define SEQ 30
#define H 64
#define VOCAB 128000

#define NB 1000
#define ITERS 8               // rows per block = 16 * ITERS = 128
#define ROWS_PER_BLOCK 128

// ws float offsets
#define WS_M 0                // [0, NB)     per-block LSE max
#define WS_S 1024             // [1024,+NB)  per-block LSE sum
#define WS_H 2048             // [2048,+64)  h_new
#define WS_FLAGS 4096         // 2 u32: flag_h, counter (memset 0 per call)

#define AGENT __HIP_MEMORY_SCOPE_AGENT

__global__ void __launch_bounds__(256, 4) fused_kernel(
        const float* __restrict__ input,
        const float* __restrict__ hidden,
        const float* __restrict__ W_ih,
        const float* __restrict__ W_hh,
        const float* __restrict__ b_ih,
        const float* __restrict__ b_hh,
        const float* __restrict__ W_out,
        const float* __restrict__ b_out,
        float* __restrict__ out,
        float* __restrict__ ws,
        unsigned* __restrict__ flags) {
    __shared__ __align__(16) float hnew[H];
    __shared__ float slog[ROWS_PER_BLOCK];
    __shared__ float pm[16], ps[16];
    __shared__ float rm[256], rs[256];

    const int t = threadIdx.x;
    const int sub = t & 15;
    const int grp = t >> 4;
    const int bid = blockIdx.x;
    const int base = bid * ROWS_PER_BLOCK;
    const float4* __restrict__ W4 = (const float4*)W_out;

    // ---- 1) all blocks: queue own W_out chunk to HBM immediately ----
    float4 w[ITERS];
    float bo[ITERS];
#pragma unroll
    for (int it = 0; it < ITERS; ++it) {
        const int row = base + it * 16 + grp;
        w[it]  = W4[row * 16 + sub];   // block-contiguous, coalesced
        bo[it] = b_out[row];
    }
    __builtin_amdgcn_sched_barrier(0);  // keep the stream issued first

    // ---- 2) h_new: block 0 computes once; others wait cheaply ----
    float4 hv;
    if (bid == 0) {
        if (t < 64) {
            // in-wave GRU (R6-validated math), lane j owns gate rows j,64+j,128+j
            const int j = t;
            float s0 = 0.f;  // softmax over singleton axis => attn weights all 1
#pragma unroll
            for (int i = 0; i < SEQ; ++i) s0 += input[i * H + j];
            const float h0 = hidden[j];
            float a0 = b_ih[j], a1 = b_ih[H + j], a2 = b_ih[2 * H + j];
            float c0 = b_hh[j], c1 = b_hh[H + j], c2 = b_hh[2 * H + j];
            const float4* Wi4 = (const float4*)W_ih;
            const float4* Wh4 = (const float4*)W_hh;
#pragma unroll
            for (int k = 0; k < H / 4; ++k) {
                const float x0 = __shfl(s0, 4 * k + 0), x1 = __shfl(s0, 4 * k + 1);
                const float x2 = __shfl(s0, 4 * k + 2), x3 = __shfl(s0, 4 * k + 3);
                const float g0 = __shfl(h0, 4 * k + 0), g1 = __shfl(h0, 4 * k + 1);
                const float g2 = __shfl(h0, 4 * k + 2), g3 = __shfl(h0, 4 * k + 3);
                float4 u;
                u = Wi4[j * 16 + k];           a0 += u.x*x0 + u.y*x1 + u.z*x2 + u.w*x3;
                u = Wi4[(H + j) * 16 + k];     a1 += u.x*x0 + u.y*x1 + u.z*x2 + u.w*x3;
                u = Wi4[(2 * H + j) * 16 + k]; a2 += u.x*x0 + u.y*x1 + u.z*x2 + u.w*x3;
                u = Wh4[j * 16 + k];           c0 += u.x*g0 + u.y*g1 + u.z*g2 + u.w*g3;
                u = Wh4[(H + j) * 16 + k];     c1 += u.x*g0 + u.y*g1 + u.z*g2 + u.w*g3;
                u = Wh4[(2 * H + j) * 16 + k]; c2 += u.x*g0 + u.y*g1 + u.z*g2 + u.w*g3;
            }
            const float r = 1.f / (1.f + expf(-(a0 + c0)));
            const float z = 1.f / (1.f + expf(-(a1 + c1)));
            const float n = tanhf(a2 + r * c2);
            const float hn = (1.f - z) * n + z * h0;
            hnew[j] = hn;
            out[VOCAB + j] = hn;  // second tuple output
            __hip_atomic_store(&ws[WS_H + j], hn, __ATOMIC_RELAXED, AGENT);
        }
        __syncthreads();  // barrier #1 (also drains wave-0 h stores)
        if (t == 0)
            __hip_atomic_store(&flags[0], 1u, __ATOMIC_RELEASE, AGENT);
        hv = ((const float4*)hnew)[sub];
    } else {
        if (t == 0) {
            // relaxed poll (sc1 load, no cache invalidate) + sleep
            while (__hip_atomic_load(&flags[0], __ATOMIC_RELAXED, AGENT) == 0u)
                __builtin_amdgcn_s_sleep(4);
        }
        __syncthreads();  // barrier #1
        hv.x = __hip_atomic_load(&ws[WS_H + sub * 4 + 0], __ATOMIC_RELAXED, AGENT);
        hv.y = __hip_atomic_load(&ws[WS_H + sub * 4 + 1], __ATOMIC_RELAXED, AGENT);
        hv.z = __hip_atomic_load(&ws[WS_H + sub * 4 + 2], __ATOMIC_RELAXED, AGENT);
        hv.w = __hip_atomic_load(&ws[WS_H + sub * 4 + 3], __ATOMIC_RELAXED, AGENT);
    }

    // ---- 3) dots + per-block LSE partial ----
    float logit[ITERS];
#pragma unroll
    for (int it = 0; it < ITERS; ++it) {
        float d = w[it].x * hv.x + w[it].y * hv.y + w[it].z * hv.z + w[it].w * hv.w;
#pragma unroll
        for (int off = 1; off < 16; off <<= 1) d += __shfl_xor(d, off);
        logit[it] = d + bo[it];
        if (sub == 0) slog[it * 16 + grp] = logit[it];
    }
    if (sub == 0) {
        float m = logit[0];
#pragma unroll
        for (int it = 1; it < ITERS; ++it) m = fmaxf(m, logit[it]);
        float s = 0.f;
#pragma unroll
        for (int it = 0; it < ITERS; ++it) s += expf(logit[it] - m);
        pm[grp] = m;
        ps[grp] = s;
    }
    __syncthreads();  // barrier #2: slog + pm/ps ready
    if (t == 0) {
        float M = pm[0], S = 0.f;
#pragma unroll
        for (int i = 1; i < 16; ++i) M = fmaxf(M, pm[i]);
#pragma unroll
        for (int i = 0; i < 16; ++i) S += ps[i] * expf(pm[i] - M);
        __hip_atomic_store(&ws[WS_M + bid], M, __ATOMIC_RELAXED, AGENT);
        __hip_atomic_store(&ws[WS_S + bid], S, __ATOMIC_RELAXED, AGENT);
        // release orders the two partial stores before the counter bump
        __hip_atomic_fetch_add(&flags[1], 1u, __ATOMIC_RELEASE, AGENT);
        // relaxed poll until all NB blocks have arrived
        while (__hip_atomic_load(&flags[1], __ATOMIC_RELAXED, AGENT) != (unsigned)NB)
            __builtin_amdgcn_s_sleep(4);
    }
    __syncthreads();  // barrier #3: counter complete

    // ---- 4) redundant LSE merge (8 KB from MALL per block) ----
    float m = -INFINITY, s = 0.f;
    for (int i = t; i < NB; i += 256) {
        const float m2 = __hip_atomic_load(&ws[WS_M + i], __ATOMIC_RELAXED, AGENT);
        const float s2 = __hip_atomic_load(&ws[WS_S + i], __ATOMIC_RELAXED, AGENT);
        const float Mn = fmaxf(m, m2);
        s = s * expf(m - Mn) + s2 * expf(m2 - Mn);
        m = Mn;
    }
    rm[t] = m; rs[t] = s;
    __syncthreads();
    for (int off = 128; off > 0; off >>= 1) {
        if (t < off) {
            const float m2 = rm[t + off], s2 = rs[t + off];
            const float Mn = fmaxf(rm[t], m2);
            rs[t] = rs[t] * expf(rm[t] - Mn) + s2 * expf(m2 - Mn);
            rm[t] = Mn;
        }
        __syncthreads();
    }
    const float lse = rm[0] + logf(rs[0]);

    // ---- 5) final store: 128 contiguous floats per block ----
    if (t < ROWS_PER_BLOCK) out[base + t] = slog[t] - lse;
}

extern "C" void kernel_launch(void* const* d_in, const int* in_sizes, int n_in,
                              void* d_out, int out_size, void* d_ws, size_t ws_size,
                              hipStream_t stream) {
    const float* input  = (const float*)d_in[0];
    const float* hidden = (const float*)d_in[1];
    // d_in[2] = W_attn, d_in[3] = b_attn: dead (softmax over singleton axis)
    const float* W_ih   = (const float*)d_in[4];
    const float* W_hh   = (const float*)d_in[5];
    const float* b_ih   = (const float*)d_in[6];
    const float* b_hh   = (const float*)d_in[7];
    const float* W_out  = (const float*)d_in[8];
    const float* b_out  = (const float*)d_in[9];
    // d_in[10] = time_step: unused
    float* out = (float*)d_out;
    float* ws  = (float*)d_ws;
    unsigned* flags = (unsigned*)((char*)d_ws + WS_FLAGS * sizeof(float));

    // zero flag_h / counter -> deterministic across graph replays
    hipMemsetAsync(flags, 0, 2 * sizeof(unsigned), stream);
    fused_kernel<<<NB, 256, 0, stream>>>(input, hidden, W_ih, W_hh, b_ih, b_hh,
                                         W_out, b_out, out, ws, flags);
}

// Round 8
// 80.211 us; speedup vs baseline: 1.1880x; 1.1880x over previous
//
#include <hip/hip_runtime.h>
#include <math.h>

#define SEQ 30
#define H 64
#define VOCAB 128000

#define NB 1000
#define ITERS 8               // rows per block = 16 * ITERS = 128
#define ROWS_PER_BLOCK 128

// ws float offsets
#define WS_M 0                // [0, NB)     per-block LSE max
#define WS_S 1024             // [1024,+NB)  per-block LSE sum
#define WS_H 2048             // [2048,+64)  h_new
#define WS_CNT 4096           // u32 arrival counter (zeroed by gru_kernel)

#define AGENT __HIP_MEMORY_SCOPE_AGENT

// ---------------- K1: attention-sum + GRU step (1 block) ----------------
__global__ void gru_kernel(const float* __restrict__ input,
                           const float* __restrict__ hidden,
                           const float* __restrict__ W_ih,
                           const float* __restrict__ W_hh,
                           const float* __restrict__ b_ih,
                           const float* __restrict__ b_hh,
                           float* __restrict__ out,
                           float* __restrict__ ws,
                           unsigned* __restrict__ cnt) {
    __shared__ float xs[H], h0s[H], gx[3 * H], gh[3 * H];
    const int t = threadIdx.x;  // 192 threads
    if (t == 0) *cnt = 0;       // reset barrier counter for this replay
    if (t < H) {
        // softmax over singleton axis => attention weights are all 1.0
        float s = 0.f;
#pragma unroll
        for (int i = 0; i < SEQ; ++i) s += input[i * H + t];
        xs[t] = s;
        h0s[t] = hidden[t];
    }
    __syncthreads();
    {
        float a = b_ih[t], b = b_hh[t];
        const float4* wi = (const float4*)(W_ih + t * H);
        const float4* wh = (const float4*)(W_hh + t * H);
        const float4* x4 = (const float4*)xs;
        const float4* h4 = (const float4*)h0s;
#pragma unroll
        for (int j = 0; j < H / 4; ++j) {
            const float4 wiv = wi[j], whv = wh[j], xv = x4[j], hv = h4[j];
            a += wiv.x * xv.x + wiv.y * xv.y + wiv.z * xv.z + wiv.w * xv.w;
            b += whv.x * hv.x + whv.y * hv.y + whv.z * hv.z + whv.w * hv.w;
        }
        gx[t] = a;
        gh[t] = b;
    }
    __syncthreads();
    if (t < H) {
        const float r = 1.f / (1.f + expf(-(gx[t] + gh[t])));
        const float z = 1.f / (1.f + expf(-(gx[H + t] + gh[H + t])));
        const float n = tanhf(gx[2 * H + t] + r * gh[2 * H + t]);
        const float hn = (1.f - z) * n + z * h0s[t];
        ws[WS_H + t] = hn;
        out[VOCAB + t] = hn;   // second tuple output: h_new
    }
}

// ---- K2: GEMV (inline loads) + LSE partial + counter barrier + merge + store
__global__ void __launch_bounds__(256, 4) logits_finish_kernel(
        const float* __restrict__ W_out,
        const float* __restrict__ b_out,
        float* __restrict__ out,
        float* __restrict__ ws,
        unsigned* __restrict__ cnt) {
    __shared__ __align__(16) float hs[H];
    __shared__ float slog[ROWS_PER_BLOCK];
    __shared__ float pm[16], ps[16];
    __shared__ float rm[256], rs[256];

    const int t = threadIdx.x;
    const int sub = t & 15;
    const int grp = t >> 4;
    const int bid = blockIdx.x;
    const int base = bid * ROWS_PER_BLOCK;
    const float4* __restrict__ W4 = (const float4*)W_out;

    if (t < H) hs[t] = ws[WS_H + t];   // kernel boundary made h_new visible
    __syncthreads();
    const float4 hv = ((const float4*)hs)[sub];

    // ---- GEMV: load inline, consume immediately (no spill-prone prefetch) ----
    float logit[ITERS];
#pragma unroll
    for (int it = 0; it < ITERS; ++it) {
        const int row = base + it * 16 + grp;
        // flat float4 index = base*16 + it*256 + t -> fully sequential per block
        const float4 w = W4[row * 16 + sub];
        float d = w.x * hv.x + w.y * hv.y + w.z * hv.z + w.w * hv.w;
#pragma unroll
        for (int off = 1; off < 16; off <<= 1) d += __shfl_xor(d, off);
        if (sub == 0) {
            const float lg = d + b_out[row];
            logit[it] = lg;
            slog[it * 16 + grp] = lg;  // parked in LDS across the wait
        }
    }
    if (sub == 0) {
        float m = logit[0];
#pragma unroll
        for (int it = 1; it < ITERS; ++it) m = fmaxf(m, logit[it]);
        float s = 0.f;
#pragma unroll
        for (int it = 0; it < ITERS; ++it) s += expf(logit[it] - m);
        pm[grp] = m;
        ps[grp] = s;
    }
    __syncthreads();

    // ---- publish partial, grid arrival barrier (t0-only relaxed poll) ----
    if (t == 0) {
        float M = pm[0], S = 0.f;
#pragma unroll
        for (int i = 1; i < 16; ++i) M = fmaxf(M, pm[i]);
#pragma unroll
        for (int i = 0; i < 16; ++i) S += ps[i] * expf(pm[i] - M);
        __hip_atomic_store(&ws[WS_M + bid], M, __ATOMIC_RELAXED, AGENT);
        __hip_atomic_store(&ws[WS_S + bid], S, __ATOMIC_RELAXED, AGENT);
        // release orders the two partial stores before the arrival bump
        __hip_atomic_fetch_add(cnt, 1u, __ATOMIC_RELEASE, AGENT);
        while (__hip_atomic_load(cnt, __ATOMIC_RELAXED, AGENT) < (unsigned)NB)
            __builtin_amdgcn_s_sleep(4);
        (void)__hip_atomic_load(cnt, __ATOMIC_ACQUIRE, AGENT);  // sync-with releases
    }
    __syncthreads();

    // ---- redundant LSE merge (8 KB from coherent point per block) ----
    float m = -INFINITY, s = 0.f;
    for (int i = t; i < NB; i += 256) {
        const float m2 = __hip_atomic_load(&ws[WS_M + i], __ATOMIC_RELAXED, AGENT);
        const float s2 = __hip_atomic_load(&ws[WS_S + i], __ATOMIC_RELAXED, AGENT);
        const float Mn = fmaxf(m, m2);
        s = s * expf(m - Mn) + s2 * expf(m2 - Mn);
        m = Mn;
    }
    rm[t] = m; rs[t] = s;
    __syncthreads();
    for (int off = 128; off > 0; off >>= 1) {
        if (t < off) {
            const float m2 = rm[t + off], s2 = rs[t + off];
            const float Mn = fmaxf(rm[t], m2);
            rs[t] = rs[t] * expf(rm[t] - Mn) + s2 * expf(m2 - Mn);
            rm[t] = Mn;
        }
        __syncthreads();
    }
    const float lse = rm[0] + logf(rs[0]);

    // ---- final store: 128 contiguous floats per block ----
    if (t < ROWS_PER_BLOCK) out[base + t] = slog[t] - lse;
}

extern "C" void kernel_launch(void* const* d_in, const int* in_sizes, int n_in,
                              void* d_out, int out_size, void* d_ws, size_t ws_size,
                              hipStream_t stream) {
    const float* input  = (const float*)d_in[0];
    const float* hidden = (const float*)d_in[1];
    // d_in[2] = W_attn, d_in[3] = b_attn: dead (softmax over singleton axis)
    const float* W_ih   = (const float*)d_in[4];
    const float* W_hh   = (const float*)d_in[5];
    const float* b_ih   = (const float*)d_in[6];
    const float* b_hh   = (const float*)d_in[7];
    const float* W_out  = (const float*)d_in[8];
    const float* b_out  = (const float*)d_in[9];
    // d_in[10] = time_step: unused
    float* out = (float*)d_out;
    float* ws  = (float*)d_ws;
    unsigned* cnt = (unsigned*)((char*)d_ws + WS_CNT * sizeof(float));

    gru_kernel<<<1, 3 * H, 0, stream>>>(input, hidden, W_ih, W_hh, b_ih, b_hh,
                                        out, ws, cnt);
    logits_finish_kernel<<<NB, 256, 0, stream>>>(W_out, b_out, out, ws, cnt);
}

// Round 9
// 24.876 us; speedup vs baseline: 3.8308x; 3.2244x over previous
//
#include <hip/hip_runtime.h>
#include <math.h>

#define SEQ 30
#define H 64
#define VOCAB 128000

#define NB 1000
#define ITERS 8               // rows per block = 16 * ITERS = 128
#define ROWS_PER_BLOCK 128

// ws layout: floats [0,64) = h_new; byte offset 512: NB x u64 packed (M,S) slots
#define WS_H 0
#define SLOT_BYTE_OFF 512
#define SENTINEL (~0ULL)

#define AGENT __HIP_MEMORY_SCOPE_AGENT

// ---------------- K1: attention-sum + GRU step (1 block) + sentinel init ----
__global__ void gru_kernel(const float* __restrict__ input,
                           const float* __restrict__ hidden,
                           const float* __restrict__ W_ih,
                           const float* __restrict__ W_hh,
                           const float* __restrict__ b_ih,
                           const float* __restrict__ b_hh,
                           float* __restrict__ out,
                           float* __restrict__ ws,
                           unsigned long long* __restrict__ slots) {
    __shared__ float xs[H], h0s[H], gx[3 * H], gh[3 * H];
    const int t = threadIdx.x;  // 192 threads
    // re-arm the sentinel slots for this replay (visible to K2 via dispatch boundary)
    for (int i = t; i < NB; i += 192) slots[i] = SENTINEL;
    if (t < H) {
        // softmax over singleton axis => attention weights are all 1.0
        float s = 0.f;
#pragma unroll
        for (int i = 0; i < SEQ; ++i) s += input[i * H + t];
        xs[t] = s;
        h0s[t] = hidden[t];
    }
    __syncthreads();
    {
        float a = b_ih[t], b = b_hh[t];
        const float4* wi = (const float4*)(W_ih + t * H);
        const float4* wh = (const float4*)(W_hh + t * H);
        const float4* x4 = (const float4*)xs;
        const float4* h4 = (const float4*)h0s;
#pragma unroll
        for (int j = 0; j < H / 4; ++j) {
            const float4 wiv = wi[j], whv = wh[j], xv = x4[j], hv = h4[j];
            a += wiv.x * xv.x + wiv.y * xv.y + wiv.z * xv.z + wiv.w * xv.w;
            b += whv.x * hv.x + whv.y * hv.y + whv.z * hv.z + whv.w * hv.w;
        }
        gx[t] = a;
        gh[t] = b;
    }
    __syncthreads();
    if (t < H) {
        const float r = 1.f / (1.f + expf(-(gx[t] + gh[t])));
        const float z = 1.f / (1.f + expf(-(gx[H + t] + gh[H + t])));
        const float n = tanhf(gx[2 * H + t] + r * gh[2 * H + t]);
        const float hn = (1.f - z) * n + z * h0s[t];
        ws[WS_H + t] = hn;
        out[VOCAB + t] = hn;   // second tuple output: h_new
    }
}

// ---- K2: GEMV (inline) + slot publish (1 relaxed 8B store, own line) +
//          sentinel-poll merge (no RMW, no acquire, no contention) + store ----
__global__ void __launch_bounds__(256, 4) logits_finish_kernel(
        const float* __restrict__ W_out,
        const float* __restrict__ b_out,
        float* __restrict__ out,
        const float* __restrict__ ws,
        unsigned long long* __restrict__ slots) {
    __shared__ __align__(16) float hs[H];
    __shared__ float slog[ROWS_PER_BLOCK];
    __shared__ float pm[16], ps[16];
    __shared__ float rm[256], rs[256];

    const int t = threadIdx.x;
    const int sub = t & 15;
    const int grp = t >> 4;
    const int bid = blockIdx.x;
    const int base = bid * ROWS_PER_BLOCK;
    const float4* __restrict__ W4 = (const float4*)W_out;

    if (t < H) hs[t] = ws[WS_H + t];   // kernel boundary made h_new visible
    __syncthreads();
    const float4 hv = ((const float4*)hs)[sub];

    // ---- GEMV: load inline, consume immediately (no spill-prone prefetch) ----
    float logit[ITERS];
#pragma unroll
    for (int it = 0; it < ITERS; ++it) {
        const int row = base + it * 16 + grp;
        // flat float4 index = base*16 + it*256 + t -> fully sequential per block
        const float4 w = W4[row * 16 + sub];
        float d = w.x * hv.x + w.y * hv.y + w.z * hv.z + w.w * hv.w;
#pragma unroll
        for (int off = 1; off < 16; off <<= 1) d += __shfl_xor(d, off);
        if (sub == 0) {
            const float lg = d + b_out[row];
            logit[it] = lg;
            slog[it * 16 + grp] = lg;  // parked in LDS across the wait
        }
    }
    if (sub == 0) {
        float m = logit[0];
#pragma unroll
        for (int it = 1; it < ITERS; ++it) m = fmaxf(m, logit[it]);
        float s = 0.f;
#pragma unroll
        for (int it = 0; it < ITERS; ++it) s += expf(logit[it] - m);
        pm[grp] = m;
        ps[grp] = s;
    }
    __syncthreads();

    // ---- publish own partial: ONE relaxed 8B store to an uncontended line ----
    if (t == 0) {
        float M = pm[0], S = 0.f;
#pragma unroll
        for (int i = 1; i < 16; ++i) M = fmaxf(M, pm[i]);
#pragma unroll
        for (int i = 0; i < 16; ++i) S += ps[i] * expf(pm[i] - M);
        const unsigned long long pk =
            ((unsigned long long)__float_as_uint(S) << 32) |
            (unsigned long long)__float_as_uint(M);
        __hip_atomic_store(&slots[bid], pk, __ATOMIC_RELAXED, AGENT);
    }

    // ---- merge all NB partials; data IS the flag (sentinel poll, relaxed) ----
    float m = -INFINITY, s = 0.f;
    for (int i = t; i < NB; i += 256) {
        unsigned long long v;
        while ((v = __hip_atomic_load(&slots[i], __ATOMIC_RELAXED, AGENT)) ==
               SENTINEL)
            __builtin_amdgcn_s_sleep(1);
        const float m2 = __uint_as_float((unsigned)(v & 0xFFFFFFFFu));
        const float s2 = __uint_as_float((unsigned)(v >> 32));
        const float Mn = fmaxf(m, m2);
        s = s * expf(m - Mn) + s2 * expf(m2 - Mn);
        m = Mn;
    }
    rm[t] = m; rs[t] = s;
    __syncthreads();
    for (int off = 128; off > 0; off >>= 1) {
        if (t < off) {
            const float m2 = rm[t + off], s2 = rs[t + off];
            const float Mn = fmaxf(rm[t], m2);
            rs[t] = rs[t] * expf(rm[t] - Mn) + s2 * expf(m2 - Mn);
            rm[t] = Mn;
        }
        __syncthreads();
    }
    const float lse = rm[0] + logf(rs[0]);

    // ---- final store: 128 contiguous floats per block ----
    if (t < ROWS_PER_BLOCK) out[base + t] = slog[t] - lse;
}

extern "C" void kernel_launch(void* const* d_in, const int* in_sizes, int n_in,
                              void* d_out, int out_size, void* d_ws, size_t ws_size,
                              hipStream_t stream) {
    const float* input  = (const float*)d_in[0];
    const float* hidden = (const float*)d_in[1];
    // d_in[2] = W_attn, d_in[3] = b_attn: dead (softmax over singleton axis)
    const float* W_ih   = (const float*)d_in[4];
    const float* W_hh   = (const float*)d_in[5];
    const float* b_ih   = (const float*)d_in[6];
    const float* b_hh   = (const float*)d_in[7];
    const float* W_out  = (const float*)d_in[8];
    const float* b_out  = (const float*)d_in[9];
    // d_in[10] = time_step: unused
    float* out = (float*)d_out;
    float* ws  = (float*)d_ws;
    unsigned long long* slots =
        (unsigned long long*)((char*)d_ws + SLOT_BYTE_OFF);

    gru_kernel<<<1, 3 * H, 0, stream>>>(input, hidden, W_ih, W_hh, b_ih, b_hh,
                                        out, ws, slots);
    logits_finish_kernel<<<NB, 256, 0, stream>>>(W_out, b_out, out, ws, slots);
}